// Round 6
// baseline (475.320 us; speedup 1.0000x reference)
//
#include <hip/hip_runtime.h>
#include <stdint.h>

typedef __attribute__((ext_vector_type(8))) short short8;
typedef __attribute__((ext_vector_type(16))) float f32x16;

#define LOG2E 1.4426950408889634f

__device__ inline float fast_exp2(float x) {
#if __has_builtin(__builtin_amdgcn_exp2f)
  return __builtin_amdgcn_exp2f(x);
#else
  float r;
  asm volatile("v_exp_f32 %0, %1" : "=v"(r) : "v"(x));
  return r;
#endif
}

// Split 8 f32 (optionally scaled) into bf16 hi + bf16 lo (truncation split;
// |x - hi - lo| <= 2^-16 |x|).
__device__ inline void split8(float x0, float x1, float x2, float x3,
                              float x4, float x5, float x6, float x7,
                              float scale, short8& hi, short8& lo) {
  float xs[8] = {x0, x1, x2, x3, x4, x5, x6, x7};
#pragma unroll
  for (int i = 0; i < 8; ++i) {
    float v = xs[i] * scale;
    unsigned u = __float_as_uint(v);
    float hf = __uint_as_float(u & 0xffff0000u);
    float rr = v - hf;  // exact
    hi[i] = (short)(u >> 16);
    lo[i] = (short)(__float_as_uint(rr) >> 16);
  }
}

// ---------------------------------------------------------------------------
// Preprocess: s[m] = exp(-||y_m||^2/2) * w[m];  pref[n] = exp(-||x_n||^2/2)
// ---------------------------------------------------------------------------
__global__ __launch_bounds__(256) void gk_prep(
    const float* __restrict__ Xnew, const float* __restrict__ Xtr,
    const float* __restrict__ w, float* __restrict__ s,
    float* __restrict__ pref, int M, int N) {
  int row = blockIdx.x * 4 + (threadIdx.x >> 6);
  int lane = threadIdx.x & 63;
  if (row >= M + N) return;
  const float* src =
      (row < M) ? (Xtr + (size_t)row * 128) : (Xnew + (size_t)(row - M) * 128);
  float2 v = *(const float2*)(src + lane * 2);
  float ss = v.x * v.x + v.y * v.y;
#pragma unroll
  for (int o = 32; o >= 1; o >>= 1) ss += __shfl_xor(ss, o, 64);
  if (lane == 0) {
    float e = expf(-0.5f * ss);
    if (row < M)
      s[row] = e * w[row];
    else
      pref[row - M] = e;
  }
}

// ---------------------------------------------------------------------------
// One-time conversion: Xtr f32 -> bf16 hi/lo planes in MFMA-FRAGMENT-TILED
// order. Per 32-row tile (16 KB): [hi 8K | lo 8K], within a plane:
// [kf(8)][lk(2)][row(32)][16B]. A wave reading (lane l: row=l&31, lk=l>>5)
// at fixed kf touches one contiguous 1 KB span -> perfectly coalesced.
// addr(T,plane,kf,lk,r) = T*16384 + plane*8192 + kf*1024 + lk*512 + r*16.
// ---------------------------------------------------------------------------
__global__ __launch_bounds__(256) void gk_conv(const float* __restrict__ Xtr,
                                               char* __restrict__ planes,
                                               int M) {
  int g = blockIdx.x * 256 + threadIdx.x;  // granule id: row*16 + gr
  int row = g >> 4;
  int gr = g & 15;  // 16B granule = 8 k-elems: kf = gr>>1, lk = gr&1
  if (row >= M) return;
  const float* p = Xtr + (size_t)row * 128 + gr * 8;
  float4 a = *(const float4*)p;
  float4 b = *(const float4*)(p + 4);
  short8 hi, lo;
  split8(a.x, a.y, a.z, a.w, b.x, b.y, b.z, b.w, 1.0f, hi, lo);
  int T = row >> 5, r = row & 31;
  int kf = gr >> 1, lk = gr & 1;
  size_t base = (size_t)T * 16384 + kf * 1024 + lk * 512 + r * 16;
  *(short8*)(planes + base) = hi;
  *(short8*)(planes + base + 8192) = lo;
}

// ---------------------------------------------------------------------------
// BARRIER-FREE main kernel. Block = 192 threads = 3 waves sharing one
// 64-col B-panel (X_new, scaled by log2e, bf16 hi/lo) in 32 KB LDS, written
// once at init (single __syncthreads in the kernel). Each wave owns its own
// 1376-row m-chunk of X_train and streams A-tiles (32 rows) global->regs
// from the fragment-tiled planes: 16 coalesced dwordx4 loads, then 48 MFMA
// (bf16x3), then exp2 epilogue. No per-iter barriers -> waves drift and
// cover each other's L2 latency; nothing large lives in registers so the
// compiler cannot rematerialize operands (the R1-R5 ~50% MfmaUtil bug).
// Grid = 1024 blocks = exactly 4/CU; launch_bounds(192,3) -> 3 waves/SIMD.
// bid&7 = m-super per XCD: each XCD's L2 holds one 2.1 MB A-slice.
// LDS layout: [plane(2)][nf(2)][kf(8)][lk(2)][col(32)][16B] = 32768 B.
// ---------------------------------------------------------------------------
__global__ __launch_bounds__(192, 3) void gk_main_fast(
    const float* __restrict__ Xnew, const char* __restrict__ planes,
    const float* __restrict__ s, const float* __restrict__ pref,
    float* __restrict__ out, int N, int M) {
  __shared__ __attribute__((aligned(16))) char blds[32768];

  const int t = threadIdx.x;
  const int l = t & 63;
  const int w = t >> 6;    // wave 0..2
  const int col = l & 31;  // own-dim index for both A-row and B-col frags
  const int lk = l >> 5;   // k-half

  // XCD-locality decode: presumed XCD = bid%8 -> one m-super per XCD.
  const int bid = blockIdx.x;   // 0..1023
  const int super = bid & 7;    // 0..7
  const int cg = bid >> 3;      // col-group 0..127
  const int n0 = cg * 64;

  // ---- B panel init: 64 cols x K=128 -> LDS (1024 granule-tasks) ----------
  for (int task = t; task < 1024; task += 192) {
    int c = task >> 4, gr = task & 15;
    const float* p = Xnew + (size_t)(n0 + c) * 128 + gr * 8;
    float4 a = *(const float4*)p;
    float4 b = *(const float4*)(p + 4);
    short8 hi, lo;
    split8(a.x, a.y, a.z, a.w, b.x, b.y, b.z, b.w, LOG2E, hi, lo);
    int kf = gr >> 1, lkk = gr & 1, nf = c >> 5;
    unsigned off = (unsigned)(nf * 8192 + kf * 1024 + lkk * 512 + (c & 31) * 16);
    *(short8*)(blds + off) = hi;
    *(short8*)(blds + 16384 + off) = lo;
  }

  // ---- wave's m-chunk ------------------------------------------------------
  const int CH = 1376;  // 43 tiles of 32; 24 chunks cover 32768 (last = 1120)
  const int m0 = (super * 3 + w) * CH;
  const int mend = (m0 + CH < M) ? (m0 + CH) : M;
  const int iters = (mend - m0) >> 5;
  const int T0 = m0 >> 5;

  __syncthreads();  // B ready; the only barrier in this kernel

  float out0 = 0.f, out1 = 0.f;
  const unsigned bcol = (unsigned)(lk * 512 + col * 16);

#pragma unroll 1
  for (int it = 0; it < iters; ++it) {
    // ---- A-tile: 16 coalesced dwordx4 global->reg loads ------------------
    const char* abase = planes + (size_t)(T0 + it) * 16384 + bcol;
    short8 ah[8], al[8];
#pragma unroll
    for (int kf = 0; kf < 8; ++kf) {
      ah[kf] = *(const short8*)(abase + kf * 1024);
      al[kf] = *(const short8*)(abase + 8192 + kf * 1024);
    }

    // ---- 48 MFMA: 2 nf x 8 kf x 3 products (bf16x3) ----------------------
    f32x16 acc0 = {0, 0, 0, 0, 0, 0, 0, 0, 0, 0, 0, 0, 0, 0, 0, 0};
    f32x16 acc1 = {0, 0, 0, 0, 0, 0, 0, 0, 0, 0, 0, 0, 0, 0, 0, 0};
    __builtin_amdgcn_s_setprio(1);
#pragma unroll
    for (int kf = 0; kf < 8; ++kf) {
      unsigned off = (unsigned)(kf * 1024) + bcol;
      short8 b0h = *(const short8*)(blds + off);
      short8 b1h = *(const short8*)(blds + 8192 + off);
      short8 b0l = *(const short8*)(blds + 16384 + off);
      short8 b1l = *(const short8*)(blds + 24576 + off);
      acc0 = __builtin_amdgcn_mfma_f32_32x32x16_bf16(ah[kf], b0h, acc0, 0, 0, 0);
      acc1 = __builtin_amdgcn_mfma_f32_32x32x16_bf16(ah[kf], b1h, acc1, 0, 0, 0);
      acc0 = __builtin_amdgcn_mfma_f32_32x32x16_bf16(ah[kf], b0l, acc0, 0, 0, 0);
      acc1 = __builtin_amdgcn_mfma_f32_32x32x16_bf16(ah[kf], b1l, acc1, 0, 0, 0);
      acc0 = __builtin_amdgcn_mfma_f32_32x32x16_bf16(al[kf], b0h, acc0, 0, 0, 0);
      acc1 = __builtin_amdgcn_mfma_f32_32x32x16_bf16(al[kf], b1h, acc1, 0, 0, 0);
    }
    __builtin_amdgcn_s_setprio(0);

    // ---- epilogue: exp2 + weighted row-sum. C/D layout (verified):
    // col = lane&31, row = (reg&3) + 8*(reg>>2) + 4*(lane>>5)
    const float* sp = s + m0 + it * 32 + 4 * lk;
#pragma unroll
    for (int q = 0; q < 4; ++q) {
      float4 sv = *(const float4*)(sp + 8 * q);
#pragma unroll
      for (int j = 0; j < 4; ++j) {
        int r = q * 4 + j;
        float svj = (&sv.x)[j];
        out0 += fast_exp2(acc0[r]) * svj;
        out1 += fast_exp2(acc1[r]) * svj;
      }
    }
  }

  // ---- cross-lane k-half reduction + atomic -------------------------------
  out0 += __shfl_xor(out0, 32, 64);
  out1 += __shfl_xor(out1, 32, 64);
  if (l < 32) {
    int n = n0 + l;
    atomicAdd(out + n, pref[n] * out0);
    n += 32;
    atomicAdd(out + n, pref[n] * out1);
  }
}

// ---------------------------------------------------------------------------
// FALLBACK (ws too small): R1 structure, loads issued after second barrier.
// ---------------------------------------------------------------------------
__device__ inline unsigned swz_fb(unsigned off) {
  return off ^ (((off >> 8) & 7u) << 4);
}

__global__ __launch_bounds__(256, 2) void gk_main_fb(
    const float* __restrict__ Xnew, const float* __restrict__ Xtr,
    const float* __restrict__ s, const float* __restrict__ pref,
    float* __restrict__ out, int N, int M, int mchunk) {
  __shared__ __attribute__((aligned(16))) char lds[33024];

  const int t = threadIdx.x;
  const int l = t & 63;
  const int w = t >> 6;
  const int lrow = l & 31;
  const int lk = l >> 5;

  const int n0 = blockIdx.x * 256;
  const int M0 = blockIdx.y * mchunk;
  const int iters = mchunk >> 6;

  short8 bh[2][8], bl[2][8];
  {
    const int colbase = n0 + w * 64;
#pragma unroll
    for (int nf = 0; nf < 2; ++nf) {
      int col = colbase + nf * 32 + lrow;
      const float* p = Xnew + (size_t)col * 128 + lk * 8;
#pragma unroll
      for (int kf = 0; kf < 8; ++kf) {
        float4 f0 = *(const float4*)(p + kf * 16);
        float4 f1 = *(const float4*)(p + kf * 16 + 4);
        split8(f0.x, f0.y, f0.z, f0.w, f1.x, f1.y, f1.z, f1.w, LOG2E,
               bh[nf][kf], bl[nf][kf]);
      }
    }
  }

  float out0 = 0.f, out1 = 0.f;
  float4 ga[4][2];
  float sreg = 0.f;

  {
    const float* abase = Xtr + (size_t)M0 * 128;
#pragma unroll
    for (int j = 0; j < 4; ++j) {
      int c = t + j * 256;
      int row = c >> 4, oct = c & 15;
      const float* p = abase + (size_t)row * 128 + oct * 8;
      ga[j][0] = *(const float4*)p;
      ga[j][1] = *(const float4*)(p + 4);
    }
    if (t < 64) sreg = s[M0 + t];
  }

#pragma unroll 1
  for (int it = 0; it < iters; ++it) {
    __syncthreads();

#pragma unroll
    for (int j = 0; j < 4; ++j) {
      int c = t + j * 256;
      int row = c >> 4, oct = c & 15;
      unsigned off = swz_fb((unsigned)(row * 256 + oct * 16));
      short8 hi, lo;
      split8(ga[j][0].x, ga[j][0].y, ga[j][0].z, ga[j][0].w, ga[j][1].x,
             ga[j][1].y, ga[j][1].z, ga[j][1].w, 1.0f, hi, lo);
      *(short8*)(lds + off) = hi;
      *(short8*)(lds + 16384 + off) = lo;
    }
    if (t < 64) *(float*)(lds + 32768 + t * 4) = sreg;

    __syncthreads();

    if (it + 1 < iters) {
      const float* abase = Xtr + (size_t)(M0 + (it + 1) * 64) * 128;
#pragma unroll
      for (int j = 0; j < 4; ++j) {
        int c = t + j * 256;
        int row = c >> 4, oct = c & 15;
        const float* p = abase + (size_t)row * 128 + oct * 8;
        ga[j][0] = *(const float4*)p;
        ga[j][1] = *(const float4*)(p + 4);
      }
      if (t < 64) sreg = s[M0 + (it + 1) * 64 + t];
    }

#pragma unroll
    for (int mf = 0; mf < 2; ++mf) {
      f32x16 acc0 = {0, 0, 0, 0, 0, 0, 0, 0, 0, 0, 0, 0, 0, 0, 0, 0};
      f32x16 acc1 = {0, 0, 0, 0, 0, 0, 0, 0, 0, 0, 0, 0, 0, 0, 0, 0};
#pragma unroll
      for (int kf = 0; kf < 8; ++kf) {
        unsigned off =
            swz_fb((unsigned)((mf * 32 + lrow) * 256 + kf * 32 + lk * 16));
        short8 ah = *(const short8*)(lds + off);
        short8 al = *(const short8*)(lds + 16384 + off);
        acc0 = __builtin_amdgcn_mfma_f32_32x32x16_bf16(ah, bh[0][kf], acc0, 0, 0, 0);
        acc1 = __builtin_amdgcn_mfma_f32_32x32x16_bf16(ah, bh[1][kf], acc1, 0, 0, 0);
        acc0 = __builtin_amdgcn_mfma_f32_32x32x16_bf16(ah, bl[0][kf], acc0, 0, 0, 0);
        acc1 = __builtin_amdgcn_mfma_f32_32x32x16_bf16(ah, bl[1][kf], acc1, 0, 0, 0);
        acc0 = __builtin_amdgcn_mfma_f32_32x32x16_bf16(al, bh[0][kf], acc0, 0, 0, 0);
        acc1 = __builtin_amdgcn_mfma_f32_32x32x16_bf16(al, bh[1][kf], acc1, 0, 0, 0);
      }
      const float* sl = (const float*)(lds + 32768 + mf * 128);
#pragma unroll
      for (int r = 0; r < 16; ++r) {
        int row = (r & 3) + 8 * (r >> 2) + 4 * lk;
        float sv = sl[row];
        out0 += fast_exp2(acc0[r]) * sv;
        out1 += fast_exp2(acc1[r]) * sv;
      }
    }
  }

  out0 += __shfl_xor(out0, 32, 64);
  out1 += __shfl_xor(out1, 32, 64);
  if (l < 32) {
    int n = n0 + w * 64 + l;
    atomicAdd(out + n, pref[n] * out0);
    n += 32;
    atomicAdd(out + n, pref[n] * out1);
  }
}

extern "C" void kernel_launch(void* const* d_in, const int* in_sizes, int n_in,
                              void* d_out, int out_size, void* d_ws,
                              size_t ws_size, hipStream_t stream) {
  const float* Xnew = (const float*)d_in[0];
  const float* Xtr = (const float*)d_in[1];
  const float* wts = (const float*)d_in[2];
  float* out = (float*)d_out;

  const int N = in_sizes[0] / 128;  // 8192
  const int M = in_sizes[1] / 128;  // 32768

  char* ws = (char*)d_ws;
  float* s_ws = (float*)ws;                   // [M]
  float* pref_ws = s_ws + M;                  // [N]
  char* planes_ws = ws + (size_t)(M + N) * 4; // [M*512 B], 16B-aligned
  const size_t need = (size_t)(M + N) * 4 + (size_t)M * 512;

  hipMemsetAsync(d_out, 0, (size_t)N * sizeof(float), stream);

  int rows = M + N;
  gk_prep<<<dim3((rows + 3) / 4), 256, 0, stream>>>(Xnew, Xtr, wts, s_ws,
                                                    pref_ws, M, N);

  if (ws_size >= need) {
    gk_conv<<<dim3(M * 16 / 256), 256, 0, stream>>>(Xtr, planes_ws, M);
    // 1024 blocks (128 col-groups x 8 m-supers) x 192 threads = 4 blocks/CU.
    gk_main_fast<<<dim3(1024), 192, 0, stream>>>(Xnew, planes_ws, s_ws,
                                                 pref_ws, out, N, M);
  } else {
    const int SPLIT = 16;
    dim3 grid(N / 256, SPLIT);
    gk_main_fb<<<grid, 256, 0, stream>>>(Xnew, Xtr, s_ws, pref_ws, out, N, M,
                                         M / SPLIT);
  }
}

// Round 7
// 185.845 us; speedup vs baseline: 2.5576x; 2.5576x over previous
//
#include <hip/hip_runtime.h>
#include <stdint.h>

typedef __attribute__((ext_vector_type(8))) short short8;
typedef __attribute__((ext_vector_type(16))) float f32x16;

#define LOG2E 1.4426950408889634f

__device__ inline float fast_exp2(float x) {
#if __has_builtin(__builtin_amdgcn_exp2f)
  return __builtin_amdgcn_exp2f(x);
#else
  float r;
  asm volatile("v_exp_f32 %0, %1" : "=v"(r) : "v"(x));
  return r;
#endif
}

__device__ inline void gload16(const void* g, void* l) {
  __builtin_amdgcn_global_load_lds(
      (const __attribute__((address_space(1))) void*)g,
      (__attribute__((address_space(3))) void*)l, 16, 0, 0);
}
__device__ inline void gload4(const void* g, void* l) {
  __builtin_amdgcn_global_load_lds(
      (const __attribute__((address_space(1))) void*)g,
      (__attribute__((address_space(3))) void*)l, 4, 0, 0);
}

// Split 8 f32 (optionally scaled) into bf16 hi + bf16 lo (truncation split;
// |x - hi - lo| <= 2^-16 |x|).
__device__ inline void split8(float x0, float x1, float x2, float x3,
                              float x4, float x5, float x6, float x7,
                              float scale, short8& hi, short8& lo) {
  float xs[8] = {x0, x1, x2, x3, x4, x5, x6, x7};
#pragma unroll
  for (int i = 0; i < 8; ++i) {
    float v = xs[i] * scale;
    unsigned u = __float_as_uint(v);
    float hf = __uint_as_float(u & 0xffff0000u);
    float rr = v - hf;  // exact
    hi[i] = (short)(u >> 16);
    lo[i] = (short)(__float_as_uint(rr) >> 16);
  }
}

// ---------------------------------------------------------------------------
// Preprocess: s[m] = exp(-||y_m||^2/2) * w[m];  pref[n] = exp(-||x_n||^2/2)
// ---------------------------------------------------------------------------
__global__ __launch_bounds__(256) void gk_prep(
    const float* __restrict__ Xnew, const float* __restrict__ Xtr,
    const float* __restrict__ w, float* __restrict__ s,
    float* __restrict__ pref, int M, int N) {
  int row = blockIdx.x * 4 + (threadIdx.x >> 6);
  int lane = threadIdx.x & 63;
  if (row >= M + N) return;
  const float* src =
      (row < M) ? (Xtr + (size_t)row * 128) : (Xnew + (size_t)(row - M) * 128);
  float2 v = *(const float2*)(src + lane * 2);
  float ss = v.x * v.x + v.y * v.y;
#pragma unroll
  for (int o = 32; o >= 1; o >>= 1) ss += __shfl_xor(ss, o, 64);
  if (lane == 0) {
    float e = expf(-0.5f * ss);
    if (row < M)
      s[row] = e * w[row];
    else
      pref[row - M] = e;
  }
}

// ---------------------------------------------------------------------------
// One-time conversion: Xtr f32 -> bf16 hi/lo in MFMA-fragment-tiled 64-row
// tiles (32 KB each): [plane(2)][kf(8)][lk(2)][row(64)][16B].
// This is byte-identical to the desired LDS image, so the main kernel's
// staging is a flat linear global_load_lds copy, and compute ds_reads are
// contiguous 512 B half-wave spans (conflict-free, no swizzle).
// ---------------------------------------------------------------------------
__global__ __launch_bounds__(256) void gk_conv(const float* __restrict__ Xtr,
                                               char* __restrict__ planes,
                                               int M) {
  int g = blockIdx.x * 256 + threadIdx.x;  // granule id: row*16 + gr
  int row = g >> 4;
  int gr = g & 15;  // 16B granule = 8 k-elems: kf = gr>>1, lk = gr&1
  if (row >= M) return;
  const float* p = Xtr + (size_t)row * 128 + gr * 8;
  float4 a = *(const float4*)p;
  float4 b = *(const float4*)(p + 4);
  short8 hi, lo;
  split8(a.x, a.y, a.z, a.w, b.x, b.y, b.z, b.w, 1.0f, hi, lo);
  int T = row >> 6, r = row & 63;
  int kf = gr >> 1, lk = gr & 1;
  size_t base = (size_t)T * 32768 + kf * 2048 + lk * 1024 + r * 16;
  *(short8*)(planes + base) = hi;          // hi plane [0,16K)
  *(short8*)(planes + base + 16384) = lo;  // lo plane [16K,32K)
}

// ---------------------------------------------------------------------------
// Main kernel: 512 threads = 8 waves; 256 output cols per block, 32 cols per
// wave -> per-wave B-panel (X_new, bf16 hi/lo, log2e-scaled) = 16 short8 =
// 64 VGPRs (register-resident, NO remat: total live ~125 under the 128-reg /
// 4-waves-per-SIMD boundary pinned by __launch_bounds__(512,4)).
// A (X_train) streams as 64-row fragment-tiled tiles through double-buffered
// LDS (2 x 32 KB + 2 x 256 B s-table = 66 KB -> 2 blocks/CU = 16 waves/CU)
// via flat global_load_lds width-16 from the pre-converted planes. Single
// barrier per iter; next-tile stage issued at top of compute so the barrier
// drain is covered by ~6k cyc of MFMA, with a second block to overlap.
// acc = log2e*<x_n,y_m>; out_n += sum_m exp2(acc)*s[m]; atomics at end.
// ---------------------------------------------------------------------------
__global__ __launch_bounds__(512, 4) void gk_main_fast(
    const float* __restrict__ Xnew, const char* __restrict__ planes,
    const float* __restrict__ s, const float* __restrict__ pref,
    float* __restrict__ out, int N, int M, int mchunk) {
  extern __shared__ char dlds[];
  // [buf0 32K][buf1 32K][s0 256][s1 256]

  const int t = threadIdx.x;
  const int l = t & 63;
  const int w = t >> 6;    // wave 0..7
  const int col = l & 31;  // frag own-index (A row / B col)
  const int lk = l >> 5;   // k-half

  const int n0 = blockIdx.x * 256;
  const int M0 = blockIdx.y * mchunk;
  const int T0 = M0 >> 6;
  const int iters = mchunk >> 6;

  // ---- prologue: stage tile 0 into buf0 (flat copy, async) ----------------
  {
    const char* src = planes + (size_t)T0 * 32768 + t * 16;
    char* dst = dlds + t * 16;
#pragma unroll
    for (int i = 0; i < 4; ++i)
      gload16(src + i * 8192, dst + i * 8192);
    if (t < 64) gload4(s + M0 + t, dlds + 65536 + t * 4);
  }

  // ---- per-wave B-panel: 32 cols, K=128, bf16 hi/lo, scaled by LOG2E ------
  short8 bh[8], bl[8];
  {
    const int c = n0 + w * 32 + col;
    const float* p = Xnew + (size_t)c * 128 + lk * 8;
#pragma unroll
    for (int kf = 0; kf < 8; ++kf) {
      float4 f0 = *(const float4*)(p + kf * 16);
      float4 f1 = *(const float4*)(p + kf * 16 + 4);
      split8(f0.x, f0.y, f0.z, f0.w, f1.x, f1.y, f1.z, f1.w, LOG2E,
             bh[kf], bl[kf]);
    }
  }

  float out0 = 0.f, out1 = 0.f;

  __syncthreads();  // tile 0 landed (vmcnt drain) + visible

#pragma unroll 1
  for (int it = 0; it < iters; ++it) {
    const int cur = it & 1;

    // ---- issue async stage of next tile into the other buffer -------------
    if (it + 1 < iters) {
      const char* src = planes + (size_t)(T0 + it + 1) * 32768 + t * 16;
      char* dst = dlds + (cur ^ 1) * 32768 + t * 16;
#pragma unroll
      for (int i = 0; i < 4; ++i)
        gload16(src + i * 8192, dst + i * 8192);
      if (t < 64)
        gload4(s + M0 + (it + 1) * 64 + t, dlds + 65536 + (cur ^ 1) * 256 + t * 4);
    }

    // ---- compute: 2 mf (64 rows) x 8 kf x 3 products = 48 MFMA ------------
    const char* buf = dlds + cur * 32768;
    f32x16 acc0 = {0, 0, 0, 0, 0, 0, 0, 0, 0, 0, 0, 0, 0, 0, 0, 0};
    f32x16 acc1 = {0, 0, 0, 0, 0, 0, 0, 0, 0, 0, 0, 0, 0, 0, 0, 0};
    __builtin_amdgcn_s_setprio(1);
#pragma unroll
    for (int kf = 0; kf < 8; ++kf) {
      const char* kb = buf + kf * 2048 + lk * 1024 + col * 16;
      short8 a0h = *(const short8*)(kb);            // mf=0 rows 0..31
      short8 a1h = *(const short8*)(kb + 512);      // mf=1 rows 32..63
      short8 a0l = *(const short8*)(kb + 16384);
      short8 a1l = *(const short8*)(kb + 16384 + 512);
      acc0 = __builtin_amdgcn_mfma_f32_32x32x16_bf16(a0h, bh[kf], acc0, 0, 0, 0);
      acc1 = __builtin_amdgcn_mfma_f32_32x32x16_bf16(a1h, bh[kf], acc1, 0, 0, 0);
      acc0 = __builtin_amdgcn_mfma_f32_32x32x16_bf16(a0h, bl[kf], acc0, 0, 0, 0);
      acc1 = __builtin_amdgcn_mfma_f32_32x32x16_bf16(a1h, bl[kf], acc1, 0, 0, 0);
      acc0 = __builtin_amdgcn_mfma_f32_32x32x16_bf16(a0l, bh[kf], acc0, 0, 0, 0);
      acc1 = __builtin_amdgcn_mfma_f32_32x32x16_bf16(a1l, bh[kf], acc1, 0, 0, 0);
    }
    __builtin_amdgcn_s_setprio(0);

    // ---- epilogue: exp2 + weighted row-sum. C/D layout (verified):
    // col = lane&31, row = (reg&3) + 8*(reg>>2) + 4*(lane>>5); +mf*32.
    const float4* sl4 = (const float4*)(dlds + 65536 + cur * 256);
#pragma unroll
    for (int q = 0; q < 4; ++q) {
      float4 sv0 = sl4[q * 2 + lk];      // mf=0 rows 8q+4lk+0..3
      float4 sv1 = sl4[8 + q * 2 + lk];  // mf=1 rows 32+8q+4lk+0..3
#pragma unroll
      for (int j = 0; j < 4; ++j) {
        int r = q * 4 + j;
        out0 += fast_exp2(acc0[r]) * (&sv0.x)[j];
        out1 += fast_exp2(acc1[r]) * (&sv1.x)[j];
      }
    }

    __syncthreads();  // drains staged loads (covered by compute above) +
                      // publishes buf cur^1; protects WAR on next overwrite
  }

  // ---- reduce k-halves + atomic -------------------------------------------
  float red = out0 + out1;
  red += __shfl_xor(red, 32, 64);
  if (l < 32) {
    int n = n0 + w * 32 + l;
    atomicAdd(out + n, pref[n] * red);
  }
}

// ---------------------------------------------------------------------------
// FALLBACK (ws too small): R1 structure, loads issued after second barrier.
// ---------------------------------------------------------------------------
__device__ inline unsigned swz_fb(unsigned off) {
  return off ^ (((off >> 8) & 7u) << 4);
}

__global__ __launch_bounds__(256, 2) void gk_main_fb(
    const float* __restrict__ Xnew, const float* __restrict__ Xtr,
    const float* __restrict__ s, const float* __restrict__ pref,
    float* __restrict__ out, int N, int M, int mchunk) {
  __shared__ __attribute__((aligned(16))) char lds[33024];

  const int t = threadIdx.x;
  const int l = t & 63;
  const int w = t >> 6;
  const int lrow = l & 31;
  const int lk = l >> 5;

  const int n0 = blockIdx.x * 256;
  const int M0 = blockIdx.y * mchunk;
  const int iters = mchunk >> 6;

  short8 bh[2][8], bl[2][8];
  {
    const int colbase = n0 + w * 64;
#pragma unroll
    for (int nf = 0; nf < 2; ++nf) {
      int col = colbase + nf * 32 + lrow;
      const float* p = Xnew + (size_t)col * 128 + lk * 8;
#pragma unroll
      for (int kf = 0; kf < 8; ++kf) {
        float4 f0 = *(const float4*)(p + kf * 16);
        float4 f1 = *(const float4*)(p + kf * 16 + 4);
        split8(f0.x, f0.y, f0.z, f0.w, f1.x, f1.y, f1.z, f1.w, LOG2E,
               bh[nf][kf], bl[nf][kf]);
      }
    }
  }

  float out0 = 0.f, out1 = 0.f;
  float4 ga[4][2];
  float sreg = 0.f;

  {
    const float* abase = Xtr + (size_t)M0 * 128;
#pragma unroll
    for (int j = 0; j < 4; ++j) {
      int c = t + j * 256;
      int row = c >> 4, oct = c & 15;
      const float* p = abase + (size_t)row * 128 + oct * 8;
      ga[j][0] = *(const float4*)p;
      ga[j][1] = *(const float4*)(p + 4);
    }
    if (t < 64) sreg = s[M0 + t];
  }

#pragma unroll 1
  for (int it = 0; it < iters; ++it) {
    __syncthreads();

#pragma unroll
    for (int j = 0; j < 4; ++j) {
      int c = t + j * 256;
      int row = c >> 4, oct = c & 15;
      unsigned off = swz_fb((unsigned)(row * 256 + oct * 16));
      short8 hi, lo;
      split8(ga[j][0].x, ga[j][0].y, ga[j][0].z, ga[j][0].w, ga[j][1].x,
             ga[j][1].y, ga[j][1].z, ga[j][1].w, 1.0f, hi, lo);
      *(short8*)(lds + off) = hi;
      *(short8*)(lds + 16384 + off) = lo;
    }
    if (t < 64) *(float*)(lds + 32768 + t * 4) = sreg;

    __syncthreads();

    if (it + 1 < iters) {
      const float* abase = Xtr + (size_t)(M0 + (it + 1) * 64) * 128;
#pragma unroll
      for (int j = 0; j < 4; ++j) {
        int c = t + j * 256;
        int row = c >> 4, oct = c & 15;
        const float* p = abase + (size_t)row * 128 + oct * 8;
        ga[j][0] = *(const float4*)p;
        ga[j][1] = *(const float4*)(p + 4);
      }
      if (t < 64) sreg = s[M0 + (it + 1) * 64 + t];
    }

#pragma unroll
    for (int mf = 0; mf < 2; ++mf) {
      f32x16 acc0 = {0, 0, 0, 0, 0, 0, 0, 0, 0, 0, 0, 0, 0, 0, 0, 0};
      f32x16 acc1 = {0, 0, 0, 0, 0, 0, 0, 0, 0, 0, 0, 0, 0, 0, 0, 0};
#pragma unroll
      for (int kf = 0; kf < 8; ++kf) {
        unsigned off =
            swz_fb((unsigned)((mf * 32 + lrow) * 256 + kf * 32 + lk * 16));
        short8 ah = *(const short8*)(lds + off);
        short8 al = *(const short8*)(lds + 16384 + off);
        acc0 = __builtin_amdgcn_mfma_f32_32x32x16_bf16(ah, bh[0][kf], acc0, 0, 0, 0);
        acc1 = __builtin_amdgcn_mfma_f32_32x32x16_bf16(ah, bh[1][kf], acc1, 0, 0, 0);
        acc0 = __builtin_amdgcn_mfma_f32_32x32x16_bf16(ah, bl[0][kf], acc0, 0, 0, 0);
        acc1 = __builtin_amdgcn_mfma_f32_32x32x16_bf16(ah, bl[1][kf], acc1, 0, 0, 0);
        acc0 = __builtin_amdgcn_mfma_f32_32x32x16_bf16(al, bh[0][kf], acc0, 0, 0, 0);
        acc1 = __builtin_amdgcn_mfma_f32_32x32x16_bf16(al, bh[1][kf], acc1, 0, 0, 0);
      }
      const float* sl = (const float*)(lds + 32768 + mf * 128);
#pragma unroll
      for (int r = 0; r < 16; ++r) {
        int row = (r & 3) + 8 * (r >> 2) + 4 * lk;
        float sv = sl[row];
        out0 += fast_exp2(acc0[r]) * sv;
        out1 += fast_exp2(acc1[r]) * sv;
      }
    }
  }

  out0 += __shfl_xor(out0, 32, 64);
  out1 += __shfl_xor(out1, 32, 64);
  if (l < 32) {
    int n = n0 + w * 64 + l;
    atomicAdd(out + n, pref[n] * out0);
    n += 32;
    atomicAdd(out + n, pref[n] * out1);
  }
}

extern "C" void kernel_launch(void* const* d_in, const int* in_sizes, int n_in,
                              void* d_out, int out_size, void* d_ws,
                              size_t ws_size, hipStream_t stream) {
  const float* Xnew = (const float*)d_in[0];
  const float* Xtr = (const float*)d_in[1];
  const float* wts = (const float*)d_in[2];
  float* out = (float*)d_out;

  const int N = in_sizes[0] / 128;  // 8192
  const int M = in_sizes[1] / 128;  // 32768

  char* ws = (char*)d_ws;
  float* s_ws = (float*)ws;                   // [M]
  float* pref_ws = s_ws + M;                  // [N]
  char* planes_ws = ws + (size_t)(M + N) * 4; // [M*512 B], 16B-aligned
  const size_t need = (size_t)(M + N) * 4 + (size_t)M * 512;

  hipMemsetAsync(d_out, 0, (size_t)N * sizeof(float), stream);

  int rows = M + N;
  gk_prep<<<dim3((rows + 3) / 4), 256, 0, stream>>>(Xnew, Xtr, wts, s_ws,
                                                    pref_ws, M, N);

  if (ws_size >= need) {
    gk_conv<<<dim3(M * 16 / 256), 256, 0, stream>>>(Xtr, planes_ws, M);
    // grid: 32 n-panels x 16 m-splits = 512 blocks x 512 thr = 2 blocks/CU.
    const int SPLIT = 16;
    dim3 grid(N / 256, SPLIT);
    gk_main_fast<<<grid, 512, 66048, stream>>>(Xnew, planes_ws, s_ws, pref_ws,
                                               out, N, M, M / SPLIT);
  } else {
    const int SPLIT = 16;
    dim3 grid(N / 256, SPLIT);
    gk_main_fb<<<grid, 256, 0, stream>>>(Xnew, Xtr, s_ws, pref_ws, out, N, M,
                                         M / SPLIT);
  }
}

// Round 8
// 142.707 us; speedup vs baseline: 3.3308x; 1.3023x over previous
//
#include <hip/hip_runtime.h>
#include <stdint.h>

typedef __attribute__((ext_vector_type(4))) int i32x4;
typedef __attribute__((ext_vector_type(16))) int i32x16;
typedef __attribute__((ext_vector_type(8))) short short8;
typedef __attribute__((ext_vector_type(16))) float f32x16;

#define LOG2E 1.4426950408889634f
// Quantization scales: A hi/lo, B hi/lo (B pre-scaled by log2e).
// Constraint sA1*sB2 == sA2*sB1 (=85250) so hl and lh share one accumulator.
#define SA1 22.0f
#define SA1_INV (1.0f / 22.0f)
#define SA2 5500.0f
#define SB1 15.5f
#define SB1_INV (1.0f / 15.5f)
#define SB2 3875.0f
#define K1 (1.0f / (22.0f * 15.5f))   // scale for hh accumulator
#define K2 (1.0f / 85250.0f)          // scale for mixed accumulator

__device__ inline float fast_exp2(float x) {
#if __has_builtin(__builtin_amdgcn_exp2f)
  return __builtin_amdgcn_exp2f(x);
#else
  float r;
  asm volatile("v_exp_f32 %0, %1" : "=v"(r) : "v"(x));
  return r;
#endif
}

__device__ inline void gload16(const void* g, void* l) {
  __builtin_amdgcn_global_load_lds(
      (const __attribute__((address_space(1))) void*)g,
      (__attribute__((address_space(3))) void*)l, 16, 0, 0);
}
__device__ inline void gload4(const void* g, void* l) {
  __builtin_amdgcn_global_load_lds(
      (const __attribute__((address_space(1))) void*)g,
      (__attribute__((address_space(3))) void*)l, 4, 0, 0);
}

// Quantize 4 floats (optionally pre-scaled) to int8 hi/lo pairs, packed into
// one int each (byte j = element j).
__device__ inline void q4(float4 v, float pre, float s1, float inv_s1,
                          float s2, int& hw, int& lw) {
  float xs[4] = {v.x, v.y, v.z, v.w};
  int h = 0, l = 0;
#pragma unroll
  for (int j = 0; j < 4; ++j) {
    float x = xs[j] * pre;
    float hf = rintf(fminf(fmaxf(x * s1, -127.f), 127.f));
    float rf = x - hf * inv_s1;
    float lf = rintf(fminf(fmaxf(rf * s2, -127.f), 127.f));
    h |= ((int)hf & 255) << (8 * j);
    l |= ((int)lf & 255) << (8 * j);
  }
  hw = h;
  lw = l;
}

// ---------------------------------------------------------------------------
// Preprocess: s[m] = exp(-||y_m||^2/2) * w[m];  pref[n] = exp(-||x_n||^2/2)
// ---------------------------------------------------------------------------
__global__ __launch_bounds__(256) void gk_prep(
    const float* __restrict__ Xnew, const float* __restrict__ Xtr,
    const float* __restrict__ w, float* __restrict__ s,
    float* __restrict__ pref, int M, int N) {
  int row = blockIdx.x * 4 + (threadIdx.x >> 6);
  int lane = threadIdx.x & 63;
  if (row >= M + N) return;
  const float* src =
      (row < M) ? (Xtr + (size_t)row * 128) : (Xnew + (size_t)(row - M) * 128);
  float2 v = *(const float2*)(src + lane * 2);
  float ss = v.x * v.x + v.y * v.y;
#pragma unroll
  for (int o = 32; o >= 1; o >>= 1) ss += __shfl_xor(ss, o, 64);
  if (lane == 0) {
    float e = expf(-0.5f * ss);
    if (row < M)
      s[row] = e * w[row];
    else
      pref[row - M] = e;
  }
}

// ---------------------------------------------------------------------------
// One-time conversion: Xtr f32 -> int8 hi/lo planes in MFMA-fragment-tiled
// 32-row tiles (8 KB each): [plane(2)][kf(4)][lk(2)][row(32)][16B].
// Byte j of a granule = k index kf*32 + lk*16 + j (same order as B packing,
// so the k-contraction is layout-consistent). LDS image = byte-identical,
// so staging is a flat linear global_load_lds copy.
// ---------------------------------------------------------------------------
__global__ __launch_bounds__(256) void gk_conv_i8(const float* __restrict__ Xtr,
                                                  char* __restrict__ planes,
                                                  int M) {
  int g = blockIdx.x * 256 + threadIdx.x;  // granule id: row*8 + gr
  int row = g >> 3;
  int gr = g & 7;  // 16 k-elems: kf = gr>>1, lk = gr&1
  if (row >= M) return;
  const float* p = Xtr + (size_t)row * 128 + gr * 16;
  int hw[4], lw[4];
#pragma unroll
  for (int i = 0; i < 4; ++i)
    q4(*(const float4*)(p + i * 4), 1.0f, SA1, SA1_INV, SA2, hw[i], lw[i]);
  int T = row >> 5, r = row & 31;
  size_t base = (size_t)T * 8192 + (gr >> 1) * 1024 + (gr & 1) * 512 + r * 16;
  *(i32x4*)(planes + base) = (i32x4){hw[0], hw[1], hw[2], hw[3]};
  *(i32x4*)(planes + base + 4096) = (i32x4){lw[0], lw[1], lw[2], lw[3]};
}

// ---------------------------------------------------------------------------
// Main kernel (i8x2 + counted-vmcnt 3-buffer pipeline).
// Block = 256 thr = 4 waves; wave tile = 32 A-rows x 64 B-cols.
// B (X_new, log2e-folded) quantized per-wave into registers: 2nf x 4kf x 2pl
// x i32x4 = 64 VGPR. A (X_train) streams as 32-row i8 tiles through
// 3-buffered LDS (3 x 8 KB + 3 x 256 B = 25 KB) via flat global_load_lds.
// Pipeline: iter t: [sched_barrier; issue stage(t+2) (3 VMEM); compute(t);
// s_waitcnt vmcnt(3) (stage(t+1) landed, NEVER 0 mid-loop); s_barrier].
// WAR safe: stage(t+2) writes buf[(t+2)%3]=buf[(t-1)%3], whose last readers
// (compute(t-1)) finished before the previous barrier.
// acc_hh*K1 + acc_mix*K2 = log2e*<x,y>; exp2; *s[m]; atomic with pref.
// Grid 32x24 = 768 = 3 blocks/CU; launch_bounds(256,3) -> <=170 VGPR.
// ---------------------------------------------------------------------------
__global__ __launch_bounds__(256, 3) void gk_main_i8(
    const float* __restrict__ Xnew, const char* __restrict__ planes,
    const float* __restrict__ s, const float* __restrict__ pref,
    float* __restrict__ out, int N, int M, int mchunk) {
  extern __shared__ char dlds[];  // [3 x 8192 A-bufs][3 x 256 s-bufs]

  const int t = threadIdx.x;
  const int l = t & 63;
  const int w = t >> 6;    // wave 0..3
  const int cl = l & 31;   // B-col within frag / A-row within frag
  const int lk = l >> 5;   // k-chunk half

  const int n0 = blockIdx.x * 256;
  const int M0 = blockIdx.y * mchunk;
  const int Mend = (M0 + mchunk < M) ? (M0 + mchunk) : M;
  const int iters = (Mend - M0) >> 5;
  const int T0 = M0 >> 5;

#define STAGE(tt, buf)                                                      \
  {                                                                         \
    const char* _src = planes + (size_t)(T0 + (tt)) * 8192 + t * 16;        \
    char* _dst = dlds + (buf)*8192 + t * 16;                                \
    gload16(_src, _dst);                                                    \
    gload16(_src + 4096, _dst + 4096);                                      \
    gload4(s + M0 + (tt)*32 + l, dlds + 24576 + (buf)*256);                 \
  }

  // ---- issue stage(0), stage(1) first so DMA overlaps B-init --------------
  STAGE(0, 0);
  if (iters > 1) STAGE(1, 1);

  // ---- per-wave B-panel: 64 cols x K=128, i8 hi/lo, log2e folded ----------
  i32x4 bh[2][4], bl[2][4];
#pragma unroll
  for (int nf = 0; nf < 2; ++nf) {
    const float* pc = Xnew + (size_t)(n0 + w * 64 + nf * 32 + cl) * 128;
#pragma unroll
    for (int kf = 0; kf < 4; ++kf) {
      const float* p = pc + kf * 32 + lk * 16;
      int hw[4], lw[4];
#pragma unroll
      for (int i = 0; i < 4; ++i)
        q4(*(const float4*)(p + i * 4), LOG2E, SB1, SB1_INV, SB2, hw[i], lw[i]);
      bh[nf][kf] = (i32x4){hw[0], hw[1], hw[2], hw[3]};
      bl[nf][kf] = (i32x4){lw[0], lw[1], lw[2], lw[3]};
    }
  }

  float out0 = 0.f, out1 = 0.f;

  asm volatile("s_waitcnt vmcnt(3)" ::: "memory");  // stage(0) landed
  __builtin_amdgcn_s_barrier();

#pragma unroll 1
  for (int it = 0; it < iters; ++it) {
    __builtin_amdgcn_sched_barrier(0);  // nothing hoists above the barrier

    // ---- issue stage(t+2) into buf[(it+2)%3] ------------------------------
    if (it + 2 < iters) STAGE(it + 2, (it + 2) % 3);

    // ---- compute tile it from buf[it%3] -----------------------------------
    const char* buf = dlds + (it % 3) * 8192;
    i32x16 acc_hh0 = {0}, acc_m0 = {0}, acc_hh1 = {0}, acc_m1 = {0};
    __builtin_amdgcn_s_setprio(1);
#pragma unroll
    for (int kf = 0; kf < 4; ++kf) {
      const char* kb = buf + kf * 1024 + lk * 512 + cl * 16;
      i32x4 ah = *(const i32x4*)(kb);
      i32x4 al = *(const i32x4*)(kb + 4096);
      acc_hh0 = __builtin_amdgcn_mfma_i32_32x32x32_i8(ah, bh[0][kf], acc_hh0, 0, 0, 0);
      acc_hh1 = __builtin_amdgcn_mfma_i32_32x32x32_i8(ah, bh[1][kf], acc_hh1, 0, 0, 0);
      acc_m0 = __builtin_amdgcn_mfma_i32_32x32x32_i8(ah, bl[0][kf], acc_m0, 0, 0, 0);
      acc_m1 = __builtin_amdgcn_mfma_i32_32x32x32_i8(ah, bl[1][kf], acc_m1, 0, 0, 0);
      acc_m0 = __builtin_amdgcn_mfma_i32_32x32x32_i8(al, bh[0][kf], acc_m0, 0, 0, 0);
      acc_m1 = __builtin_amdgcn_mfma_i32_32x32x32_i8(al, bh[1][kf], acc_m1, 0, 0, 0);
    }
    __builtin_amdgcn_s_setprio(0);

    // ---- epilogue: c = hh*K1 + mix*K2 (= log2e * <x,y>); exp2; * s[m] -----
    // C/D layout (verified): col = lane&31, row = (reg&3)+8*(reg>>2)+4*lk
    const float4* sl4 = (const float4*)(dlds + 24576 + (it % 3) * 256);
#pragma unroll
    for (int q = 0; q < 4; ++q) {
      float4 sv = sl4[q * 2 + lk];
#pragma unroll
      for (int j = 0; j < 4; ++j) {
        int r = q * 4 + j;
        float svj = (&sv.x)[j];
        float c0 = (float)acc_hh0[r] * K1 + (float)acc_m0[r] * K2;
        float c1 = (float)acc_hh1[r] * K1 + (float)acc_m1[r] * K2;
        out0 += fast_exp2(c0) * svj;
        out1 += fast_exp2(c1) * svj;
      }
    }

    // ---- counted wait (stage(t+1) landed; never drain to 0 mid-loop) ------
    if (it + 1 < iters) {
      if (it + 2 < iters) {
        asm volatile("s_waitcnt vmcnt(3)" ::: "memory");
      } else {
        asm volatile("s_waitcnt vmcnt(0)" ::: "memory");
      }
      __builtin_amdgcn_s_barrier();
    }
  }

  // ---- reduce row-halves (lane>>5) + atomic -------------------------------
  out0 += __shfl_xor(out0, 32, 64);
  out1 += __shfl_xor(out1, 32, 64);
  if (l < 32) {
    int n = n0 + w * 64 + l;
    atomicAdd(out + n, pref[n] * out0);
    n += 32;
    atomicAdd(out + n, pref[n] * out1);
  }
#undef STAGE
}

// ---------------------------------------------------------------------------
// FALLBACK (ws too small): R1-structure bf16x3 (known-good at ~185 us).
// ---------------------------------------------------------------------------
__device__ inline unsigned swz_fb(unsigned off) {
  return off ^ (((off >> 8) & 7u) << 4);
}
__device__ inline void split8(float x0, float x1, float x2, float x3,
                              float x4, float x5, float x6, float x7,
                              float scale, short8& hi, short8& lo) {
  float xs[8] = {x0, x1, x2, x3, x4, x5, x6, x7};
#pragma unroll
  for (int i = 0; i < 8; ++i) {
    float v = xs[i] * scale;
    unsigned u = __float_as_uint(v);
    float hf = __uint_as_float(u & 0xffff0000u);
    float rr = v - hf;
    hi[i] = (short)(u >> 16);
    lo[i] = (short)(__float_as_uint(rr) >> 16);
  }
}

__global__ __launch_bounds__(256, 2) void gk_main_fb(
    const float* __restrict__ Xnew, const float* __restrict__ Xtr,
    const float* __restrict__ s, const float* __restrict__ pref,
    float* __restrict__ out, int N, int M, int mchunk) {
  __shared__ __attribute__((aligned(16))) char lds[33024];
  const int t = threadIdx.x;
  const int l = t & 63;
  const int w = t >> 6;
  const int lrow = l & 31;
  const int lk = l >> 5;
  const int n0 = blockIdx.x * 256;
  const int M0 = blockIdx.y * mchunk;
  const int iters = mchunk >> 6;

  short8 bh[2][8], bl[2][8];
  {
    const int colbase = n0 + w * 64;
#pragma unroll
    for (int nf = 0; nf < 2; ++nf) {
      int col = colbase + nf * 32 + lrow;
      const float* p = Xnew + (size_t)col * 128 + lk * 8;
#pragma unroll
      for (int kf = 0; kf < 8; ++kf) {
        float4 f0 = *(const float4*)(p + kf * 16);
        float4 f1 = *(const float4*)(p + kf * 16 + 4);
        split8(f0.x, f0.y, f0.z, f0.w, f1.x, f1.y, f1.z, f1.w, LOG2E,
               bh[nf][kf], bl[nf][kf]);
      }
    }
  }

  float out0 = 0.f, out1 = 0.f;
  float4 ga[4][2];
  float sreg = 0.f;
  {
    const float* abase = Xtr + (size_t)M0 * 128;
#pragma unroll
    for (int j = 0; j < 4; ++j) {
      int c = t + j * 256;
      int row = c >> 4, oct = c & 15;
      const float* p = abase + (size_t)row * 128 + oct * 8;
      ga[j][0] = *(const float4*)p;
      ga[j][1] = *(const float4*)(p + 4);
    }
    if (t < 64) sreg = s[M0 + t];
  }

#pragma unroll 1
  for (int it = 0; it < iters; ++it) {
    __syncthreads();
#pragma unroll
    for (int j = 0; j < 4; ++j) {
      int c = t + j * 256;
      int row = c >> 4, oct = c & 15;
      unsigned off = swz_fb((unsigned)(row * 256 + oct * 16));
      short8 hi, lo;
      split8(ga[j][0].x, ga[j][0].y, ga[j][0].z, ga[j][0].w, ga[j][1].x,
             ga[j][1].y, ga[j][1].z, ga[j][1].w, 1.0f, hi, lo);
      *(short8*)(lds + off) = hi;
      *(short8*)(lds + 16384 + off) = lo;
    }
    if (t < 64) *(float*)(lds + 32768 + t * 4) = sreg;
    __syncthreads();
    if (it + 1 < iters) {
      const float* abase = Xtr + (size_t)(M0 + (it + 1) * 64) * 128;
#pragma unroll
      for (int j = 0; j < 4; ++j) {
        int c = t + j * 256;
        int row = c >> 4, oct = c & 15;
        const float* p = abase + (size_t)row * 128 + oct * 8;
        ga[j][0] = *(const float4*)p;
        ga[j][1] = *(const float4*)(p + 4);
      }
      if (t < 64) sreg = s[M0 + (it + 1) * 64 + t];
    }
#pragma unroll
    for (int mf = 0; mf < 2; ++mf) {
      f32x16 acc0 = {0, 0, 0, 0, 0, 0, 0, 0, 0, 0, 0, 0, 0, 0, 0, 0};
      f32x16 acc1 = {0, 0, 0, 0, 0, 0, 0, 0, 0, 0, 0, 0, 0, 0, 0, 0};
#pragma unroll
      for (int kf = 0; kf < 8; ++kf) {
        unsigned off =
            swz_fb((unsigned)((mf * 32 + lrow) * 256 + kf * 32 + lk * 16));
        short8 ah = *(const short8*)(lds + off);
        short8 al = *(const short8*)(lds + 16384 + off);
        acc0 = __builtin_amdgcn_mfma_f32_32x32x16_bf16(ah, bh[0][kf], acc0, 0, 0, 0);
        acc1 = __builtin_amdgcn_mfma_f32_32x32x16_bf16(ah, bh[1][kf], acc1, 0, 0, 0);
        acc0 = __builtin_amdgcn_mfma_f32_32x32x16_bf16(ah, bl[0][kf], acc0, 0, 0, 0);
        acc1 = __builtin_amdgcn_mfma_f32_32x32x16_bf16(ah, bl[1][kf], acc1, 0, 0, 0);
        acc0 = __builtin_amdgcn_mfma_f32_32x32x16_bf16(al, bh[0][kf], acc0, 0, 0, 0);
        acc1 = __builtin_amdgcn_mfma_f32_32x32x16_bf16(al, bh[1][kf], acc1, 0, 0, 0);
      }
      const float* sl = (const float*)(lds + 32768 + mf * 128);
#pragma unroll
      for (int r = 0; r < 16; ++r) {
        int row = (r & 3) + 8 * (r >> 2) + 4 * lk;
        float sv = sl[row];
        out0 += fast_exp2(acc0[r]) * sv;
        out1 += fast_exp2(acc1[r]) * sv;
      }
    }
  }
  out0 += __shfl_xor(out0, 32, 64);
  out1 += __shfl_xor(out1, 32, 64);
  if (l < 32) {
    int n = n0 + w * 64 + l;
    atomicAdd(out + n, pref[n] * out0);
    n += 32;
    atomicAdd(out + n, pref[n] * out1);
  }
}

extern "C" void kernel_launch(void* const* d_in, const int* in_sizes, int n_in,
                              void* d_out, int out_size, void* d_ws,
                              size_t ws_size, hipStream_t stream) {
  const float* Xnew = (const float*)d_in[0];
  const float* Xtr = (const float*)d_in[1];
  const float* wts = (const float*)d_in[2];
  float* out = (float*)d_out;

  const int N = in_sizes[0] / 128;  // 8192
  const int M = in_sizes[1] / 128;  // 32768

  char* ws = (char*)d_ws;
  float* s_ws = (float*)ws;                    // [M]
  float* pref_ws = s_ws + M;                   // [N]
  char* planes_ws = ws + (size_t)(M + N) * 4;  // [M*256 B], 16B-aligned
  const size_t need = (size_t)(M + N) * 4 + (size_t)M * 256;

  hipMemsetAsync(d_out, 0, (size_t)N * sizeof(float), stream);

  int rows = M + N;
  gk_prep<<<dim3((rows + 3) / 4), 256, 0, stream>>>(Xnew, Xtr, wts, s_ws,
                                                    pref_ws, M, N);

  if (ws_size >= need) {
    gk_conv_i8<<<dim3(M * 8 / 256), 256, 0, stream>>>(Xtr, planes_ws, M);
    const int SPLIT = 24;  // 32 x 24 = 768 blocks = exactly 3 per CU
    const int CH = ((M + SPLIT - 1) / SPLIT + 31) & ~31;  // 1376
    dim3 grid(N / 256, SPLIT);
    gk_main_i8<<<grid, 256, 25344, stream>>>(Xnew, planes_ws, s_ws, pref_ws,
                                             out, N, M, CH);
  } else {
    const int SPLIT = 16;
    dim3 grid(N / 256, SPLIT);
    gk_main_fb<<<grid, 256, 0, stream>>>(Xnew, Xtr, s_ws, pref_ws, out, N, M,
                                         M / SPLIT);
  }
}

// Round 9
// 131.231 us; speedup vs baseline: 3.6220x; 1.0874x over previous
//
#include <hip/hip_runtime.h>
#include <stdint.h>

typedef __attribute__((ext_vector_type(4))) int i32x4;
typedef __attribute__((ext_vector_type(16))) int i32x16;
typedef __attribute__((ext_vector_type(8))) short short8;
typedef __attribute__((ext_vector_type(16))) float f32x16;

#define LOG2E 1.4426950408889634f
// Power-of-2 quantization scales (A raw, B pre-scaled by log2e):
//   hi = rint(x*16), lo = rint((x - hi/16)*4096)
//   K1 = 1/(16*16) = 1/256, K2 = 1/(16*4096) = 1/65536, K1/K2 = 256
//   => c = (float)((hh << 8) + m) * 2^-16   (one lshl_add + cvt + mul)
#define S1 16.0f
#define S1_INV 0.0625f
#define S2 4096.0f
#define K2 (1.0f / 65536.0f)

__device__ inline float fast_exp2(float x) {
#if __has_builtin(__builtin_amdgcn_exp2f)
  return __builtin_amdgcn_exp2f(x);
#else
  float r;
  asm volatile("v_exp_f32 %0, %1" : "=v"(r) : "v"(x));
  return r;
#endif
}

__device__ inline void gload16(const void* g, void* l) {
  __builtin_amdgcn_global_load_lds(
      (const __attribute__((address_space(1))) void*)g,
      (__attribute__((address_space(3))) void*)l, 16, 0, 0);
}
__device__ inline void gload4(const void* g, void* l) {
  __builtin_amdgcn_global_load_lds(
      (const __attribute__((address_space(1))) void*)g,
      (__attribute__((address_space(3))) void*)l, 4, 0, 0);
}

// Quantize 4 floats (optionally pre-scaled) to int8 hi/lo pairs, packed into
// one int each (byte j = element j).
__device__ inline void q4(float4 v, float pre, int& hw, int& lw) {
  float xs[4] = {v.x, v.y, v.z, v.w};
  int h = 0, l = 0;
#pragma unroll
  for (int j = 0; j < 4; ++j) {
    float x = xs[j] * pre;
    float hf = rintf(fminf(fmaxf(x * S1, -127.f), 127.f));
    float rf = x - hf * S1_INV;
    float lf = rintf(fminf(fmaxf(rf * S2, -127.f), 127.f));
    h |= ((int)hf & 255) << (8 * j);
    l |= ((int)lf & 255) << (8 * j);
  }
  hw = h;
  lw = l;
}

// ---------------------------------------------------------------------------
// Preprocess: s[m] = exp(-||y_m||^2/2) * w[m];  pref[n] = exp(-||x_n||^2/2)
// ---------------------------------------------------------------------------
__global__ __launch_bounds__(256) void gk_prep(
    const float* __restrict__ Xnew, const float* __restrict__ Xtr,
    const float* __restrict__ w, float* __restrict__ s,
    float* __restrict__ pref, int M, int N) {
  int row = blockIdx.x * 4 + (threadIdx.x >> 6);
  int lane = threadIdx.x & 63;
  if (row >= M + N) return;
  const float* src =
      (row < M) ? (Xtr + (size_t)row * 128) : (Xnew + (size_t)(row - M) * 128);
  float2 v = *(const float2*)(src + lane * 2);
  float ss = v.x * v.x + v.y * v.y;
#pragma unroll
  for (int o = 32; o >= 1; o >>= 1) ss += __shfl_xor(ss, o, 64);
  if (lane == 0) {
    float e = expf(-0.5f * ss);
    if (row < M)
      s[row] = e * w[row];
    else
      pref[row - M] = e;
  }
}

// ---------------------------------------------------------------------------
// One-time conversion: Xtr f32 -> int8 hi/lo planes in MFMA-fragment-tiled
// 32-row tiles (8 KB each): [plane(2)][kf(4)][lk(2)][row(32)][16B].
// Byte j of a granule = k index kf*32 + lk*16 + j (same order as B packing).
// LDS image is byte-identical, so staging is one flat global_load_lds.
// ---------------------------------------------------------------------------
__global__ __launch_bounds__(256) void gk_conv_i8(const float* __restrict__ Xtr,
                                                  char* __restrict__ planes,
                                                  int M) {
  int g = blockIdx.x * 256 + threadIdx.x;  // granule id: row*8 + gr
  int row = g >> 3;
  int gr = g & 7;  // 16 k-elems: kf = gr>>1, lk = gr&1
  if (row >= M) return;
  const float* p = Xtr + (size_t)row * 128 + gr * 16;
  int hw[4], lw[4];
#pragma unroll
  for (int i = 0; i < 4; ++i)
    q4(*(const float4*)(p + i * 4), 1.0f, hw[i], lw[i]);
  int T = row >> 5, r = row & 31;
  size_t base = (size_t)T * 8192 + (gr >> 1) * 1024 + (gr & 1) * 512 + r * 16;
  *(i32x4*)(planes + base) = (i32x4){hw[0], hw[1], hw[2], hw[3]};
  *(i32x4*)(planes + base + 4096) = (i32x4){lw[0], lw[1], lw[2], lw[3]};
}

// ---------------------------------------------------------------------------
// Main kernel (i8x2, all-VGPR wave tiles, counted-vmcnt 3-buffer pipeline).
// Block = 512 thr = 8 waves; wave tile = 32 A-rows x 32 B-cols.
// Per-wave regs: B = 8 x i32x4 = 32, acc = 2 x i32x16 = 32, live ~100 <= 128
// cap from __launch_bounds__(512,4) -> 4 waves/SIMD, NO AGPR shuttling (the
// R8 VALU=49% bug). A (X_train) streams as 32-row i8 tiles through 3-buffered
// LDS; with 512 threads ONE gload16 stages a whole 8 KB tile (2 VMEM/thread/
// iter incl. the s-chunk gload4).
// Pipeline per iter t: [sched_barrier; issue stage(t+2); 12 MFMA; epilogue;
// s_waitcnt vmcnt(2) (stage(t+1) landed, never 0 mid-loop); s_barrier].
// WAR safe: stage(t+2) writes buf[(t-1)%3], whose readers (compute(t-1))
// finished before the trailing barrier of iter t-1.
// c = ((hh<<8)+m)*2^-16 = log2e*<x,y>; exp2; *s[m]; atomic with pref.
// Grid 32x16 = 512 blocks = exactly 2 per CU (16 waves/CU).
// ---------------------------------------------------------------------------
__global__ __launch_bounds__(512, 4) void gk_main_i8(
    const float* __restrict__ Xnew, const char* __restrict__ planes,
    const float* __restrict__ s, const float* __restrict__ pref,
    float* __restrict__ out, int N, int M, int mchunk) {
  extern __shared__ char dlds[];  // [3 x 8192 A-bufs][3 x 256 s-bufs]

  const int t = threadIdx.x;
  const int l = t & 63;
  const int w = t >> 6;   // wave 0..7
  const int cl = l & 31;  // B-col within frag / A-row within frag
  const int lk = l >> 5;  // k-chunk half

  const int n0 = blockIdx.x * 256;
  const int M0 = blockIdx.y * mchunk;
  const int iters = mchunk >> 5;
  const int T0 = M0 >> 5;

#define STAGE(tt, buf)                                                 \
  {                                                                    \
    gload16(planes + (size_t)(T0 + (tt)) * 8192 + t * 16,              \
            dlds + (buf)*8192 + t * 16);                               \
    gload4(s + M0 + (tt)*32 + l, dlds + 24576 + (buf)*256);            \
  }

  // ---- issue stage(0), stage(1) first so DMA overlaps B-init --------------
  STAGE(0, 0);
  if (iters > 1) STAGE(1, 1);

  // ---- per-wave B-panel: 32 cols x K=128, i8 hi/lo, log2e folded ----------
  i32x4 bh[4], bl[4];
  {
    const float* pc = Xnew + (size_t)(n0 + w * 32 + cl) * 128;
#pragma unroll
    for (int kf = 0; kf < 4; ++kf) {
      const float* p = pc + kf * 32 + lk * 16;
      int hw[4], lw[4];
#pragma unroll
      for (int i = 0; i < 4; ++i)
        q4(*(const float4*)(p + i * 4), LOG2E, hw[i], lw[i]);
      bh[kf] = (i32x4){hw[0], hw[1], hw[2], hw[3]};
      bl[kf] = (i32x4){lw[0], lw[1], lw[2], lw[3]};
    }
  }

  float out0 = 0.f;

  if (iters > 1) {
    asm volatile("s_waitcnt vmcnt(2)" ::: "memory");  // stage(0) landed
  } else {
    asm volatile("s_waitcnt vmcnt(0)" ::: "memory");
  }
  __builtin_amdgcn_s_barrier();

#pragma unroll 1
  for (int it = 0; it < iters; ++it) {
    __builtin_amdgcn_sched_barrier(0);  // nothing hoists above the barrier

    // ---- issue stage(t+2) into buf[(it+2)%3] ------------------------------
    if (it + 2 < iters) STAGE(it + 2, (it + 2) % 3);

    // ---- compute tile it from buf[it%3]: 4 kf x 3 products = 12 MFMA ------
    const char* buf = dlds + (it % 3) * 8192;
    i32x16 acc_hh = {0}, acc_m = {0};
    __builtin_amdgcn_s_setprio(1);
#pragma unroll
    for (int kf = 0; kf < 4; ++kf) {
      const char* kb = buf + kf * 1024 + lk * 512 + cl * 16;
      i32x4 ah = *(const i32x4*)(kb);
      i32x4 al = *(const i32x4*)(kb + 4096);
      acc_hh = __builtin_amdgcn_mfma_i32_32x32x32_i8(ah, bh[kf], acc_hh, 0, 0, 0);
      acc_m = __builtin_amdgcn_mfma_i32_32x32x32_i8(ah, bl[kf], acc_m, 0, 0, 0);
      acc_m = __builtin_amdgcn_mfma_i32_32x32x32_i8(al, bh[kf], acc_m, 0, 0, 0);
    }
    __builtin_amdgcn_s_setprio(0);

    // ---- epilogue: c = ((hh<<8)+m)*2^-16 (= log2e*<x,y>); exp2; *s[m] -----
    // C/D layout (verified): col = lane&31, row = (reg&3)+8*(reg>>2)+4*lk
    const float4* sl4 = (const float4*)(dlds + 24576 + (it % 3) * 256);
#pragma unroll
    for (int q = 0; q < 4; ++q) {
      float4 sv = sl4[q * 2 + lk];
#pragma unroll
      for (int j = 0; j < 4; ++j) {
        int r = q * 4 + j;
        float c = (float)((acc_hh[r] << 8) + acc_m[r]) * K2;
        out0 += fast_exp2(c) * (&sv.x)[j];
      }
    }

    // ---- counted wait (stage(t+1) landed; never drain to 0 mid-loop) ------
    if (it + 1 < iters) {
      if (it + 2 < iters) {
        asm volatile("s_waitcnt vmcnt(2)" ::: "memory");
      } else {
        asm volatile("s_waitcnt vmcnt(0)" ::: "memory");
      }
      __builtin_amdgcn_s_barrier();
    }
  }

  // ---- reduce row-halves (lane>>5) + atomic -------------------------------
  out0 += __shfl_xor(out0, 32, 64);
  if (l < 32) {
    int n = n0 + w * 32 + l;
    atomicAdd(out + n, pref[n] * out0);
  }
#undef STAGE
}

// ---------------------------------------------------------------------------
// FALLBACK (ws too small): R1-structure bf16x3 (known-good at ~185 us).
// ---------------------------------------------------------------------------
__device__ inline unsigned swz_fb(unsigned off) {
  return off ^ (((off >> 8) & 7u) << 4);
}
__device__ inline void split8(float x0, float x1, float x2, float x3,
                              float x4, float x5, float x6, float x7,
                              float scale, short8& hi, short8& lo) {
  float xs[8] = {x0, x1, x2, x3, x4, x5, x6, x7};
#pragma unroll
  for (int i = 0; i < 8; ++i) {
    float v = xs[i] * scale;
    unsigned u = __float_as_uint(v);
    float hf = __uint_as_float(u & 0xffff0000u);
    float rr = v - hf;
    hi[i] = (short)(u >> 16);
    lo[i] = (short)(__float_as_uint(rr) >> 16);
  }
}

__global__ __launch_bounds__(256, 2) void gk_main_fb(
    const float* __restrict__ Xnew, const float* __restrict__ Xtr,
    const float* __restrict__ s, const float* __restrict__ pref,
    float* __restrict__ out, int N, int M, int mchunk) {
  __shared__ __attribute__((aligned(16))) char lds[33024];
  const int t = threadIdx.x;
  const int l = t & 63;
  const int w = t >> 6;
  const int lrow = l & 31;
  const int lk = l >> 5;
  const int n0 = blockIdx.x * 256;
  const int M0 = blockIdx.y * mchunk;
  const int iters = mchunk >> 6;

  short8 bh[2][8], bl[2][8];
  {
    const int colbase = n0 + w * 64;
#pragma unroll
    for (int nf = 0; nf < 2; ++nf) {
      int col = colbase + nf * 32 + lrow;
      const float* p = Xnew + (size_t)col * 128 + lk * 8;
#pragma unroll
      for (int kf = 0; kf < 8; ++kf) {
        float4 f0 = *(const float4*)(p + kf * 16);
        float4 f1 = *(const float4*)(p + kf * 16 + 4);
        split8(f0.x, f0.y, f0.z, f0.w, f1.x, f1.y, f1.z, f1.w, LOG2E,
               bh[nf][kf], bl[nf][kf]);
      }
    }
  }

  float out0 = 0.f, out1 = 0.f;
  float4 ga[4][2];
  float sreg = 0.f;
  {
    const float* abase = Xtr + (size_t)M0 * 128;
#pragma unroll
    for (int j = 0; j < 4; ++j) {
      int c = t + j * 256;
      int row = c >> 4, oct = c & 15;
      const float* p = abase + (size_t)row * 128 + oct * 8;
      ga[j][0] = *(const float4*)p;
      ga[j][1] = *(const float4*)(p + 4);
    }
    if (t < 64) sreg = s[M0 + t];
  }

#pragma unroll 1
  for (int it = 0; it < iters; ++it) {
    __syncthreads();
#pragma unroll
    for (int j = 0; j < 4; ++j) {
      int c = t + j * 256;
      int row = c >> 4, oct = c & 15;
      unsigned off = swz_fb((unsigned)(row * 256 + oct * 16));
      short8 hi, lo;
      split8(ga[j][0].x, ga[j][0].y, ga[j][0].z, ga[j][0].w, ga[j][1].x,
             ga[j][1].y, ga[j][1].z, ga[j][1].w, 1.0f, hi, lo);
      *(short8*)(lds + off) = hi;
      *(short8*)(lds + 16384 + off) = lo;
    }
    if (t < 64) *(float*)(lds + 32768 + t * 4) = sreg;
    __syncthreads();
    if (it + 1 < iters) {
      const float* abase = Xtr + (size_t)(M0 + (it + 1) * 64) * 128;
#pragma unroll
      for (int j = 0; j < 4; ++j) {
        int c = t + j * 256;
        int row = c >> 4, oct = c & 15;
        const float* p = abase + (size_t)row * 128 + oct * 8;
        ga[j][0] = *(const float4*)p;
        ga[j][1] = *(const float4*)(p + 4);
      }
      if (t < 64) sreg = s[M0 + (it + 1) * 64 + t];
    }
#pragma unroll
    for (int mf = 0; mf < 2; ++mf) {
      f32x16 acc0 = {0, 0, 0, 0, 0, 0, 0, 0, 0, 0, 0, 0, 0, 0, 0, 0};
      f32x16 acc1 = {0, 0, 0, 0, 0, 0, 0, 0, 0, 0, 0, 0, 0, 0, 0, 0};
#pragma unroll
      for (int kf = 0; kf < 8; ++kf) {
        unsigned off =
            swz_fb((unsigned)((mf * 32 + lrow) * 256 + kf * 32 + lk * 16));
        short8 ah = *(const short8*)(lds + off);
        short8 al = *(const short8*)(lds + 16384 + off);
        acc0 = __builtin_amdgcn_mfma_f32_32x32x16_bf16(ah, bh[0][kf], acc0, 0, 0, 0);
        acc1 = __builtin_amdgcn_mfma_f32_32x32x16_bf16(ah, bh[1][kf], acc1, 0, 0, 0);
        acc0 = __builtin_amdgcn_mfma_f32_32x32x16_bf16(ah, bl[0][kf], acc0, 0, 0, 0);
        acc1 = __builtin_amdgcn_mfma_f32_32x32x16_bf16(ah, bl[1][kf], acc1, 0, 0, 0);
        acc0 = __builtin_amdgcn_mfma_f32_32x32x16_bf16(al, bh[0][kf], acc0, 0, 0, 0);
        acc1 = __builtin_amdgcn_mfma_f32_32x32x16_bf16(al, bh[1][kf], acc1, 0, 0, 0);
      }
      const float* sl = (const float*)(lds + 32768 + mf * 128);
#pragma unroll
      for (int r = 0; r < 16; ++r) {
        int row = (r & 3) + 8 * (r >> 2) + 4 * lk;
        float sv = sl[row];
        out0 += fast_exp2(acc0[r]) * sv;
        out1 += fast_exp2(acc1[r]) * sv;
      }
    }
  }
  out0 += __shfl_xor(out0, 32, 64);
  out1 += __shfl_xor(out1, 32, 64);
  if (l < 32) {
    int n = n0 + w * 64 + l;
    atomicAdd(out + n, pref[n] * out0);
    n += 32;
    atomicAdd(out + n, pref[n] * out1);
  }
}

extern "C" void kernel_launch(void* const* d_in, const int* in_sizes, int n_in,
                              void* d_out, int out_size, void* d_ws,
                              size_t ws_size, hipStream_t stream) {
  const float* Xnew = (const float*)d_in[0];
  const float* Xtr = (const float*)d_in[1];
  const float* wts = (const float*)d_in[2];
  float* out = (float*)d_out;

  const int N = in_sizes[0] / 128;  // 8192
  const int M = in_sizes[1] / 128;  // 32768

  char* ws = (char*)d_ws;
  float* s_ws = (float*)ws;                    // [M]
  float* pref_ws = s_ws + M;                   // [N]
  char* planes_ws = ws + (size_t)(M + N) * 4;  // [M*256 B], 16B-aligned
  const size_t need = (size_t)(M + N) * 4 + (size_t)M * 256;

  hipMemsetAsync(d_out, 0, (size_t)N * sizeof(float), stream);

  int rows = M + N;
  gk_prep<<<dim3((rows + 3) / 4), 256, 0, stream>>>(Xnew, Xtr, wts, s_ws,
                                                    pref_ws, M, N);

  if (ws_size >= need) {
    gk_conv_i8<<<dim3(M * 8 / 256), 256, 0, stream>>>(Xtr, planes_ws, M);
    const int SPLIT = 16;  // 32 x 16 = 512 blocks = exactly 2 per CU
    dim3 grid(N / 256, SPLIT);
    gk_main_i8<<<grid, 512, 25344, stream>>>(Xnew, planes_ws, s_ws, pref_ws,
                                             out, N, M, M / SPLIT);
  } else {
    const int SPLIT = 16;
    dim3 grid(N / 256, SPLIT);
    gk_main_fb<<<grid, 256, 0, stream>>>(Xnew, Xtr, s_ws, pref_ws, out, N, M,
                                         M / SPLIT);
  }
}

// Round 10
// 122.172 us; speedup vs baseline: 3.8906x; 1.0742x over previous
//
#include <hip/hip_runtime.h>
#include <stdint.h>

typedef __attribute__((ext_vector_type(4))) int i32x4;
typedef __attribute__((ext_vector_type(16))) int i32x16;
typedef __attribute__((ext_vector_type(8))) short short8;
typedef __attribute__((ext_vector_type(16))) float f32x16;

#define LOG2E 1.4426950408889634f
// Power-of-2 quantization scales (A raw, B pre-scaled by log2e):
//   hi = rint(x*16), lo = rint((x - hi/16)*4096)
//   c = (float)((hh << 8) + m) * 2^-16
#define S1 16.0f
#define S1_INV 0.0625f
#define S2 4096.0f
#define K2 (1.0f / 65536.0f)

__device__ inline float fast_exp2(float x) {
#if __has_builtin(__builtin_amdgcn_exp2f)
  return __builtin_amdgcn_exp2f(x);
#else
  float r;
  asm volatile("v_exp_f32 %0, %1" : "=v"(r) : "v"(x));
  return r;
#endif
}

__device__ inline void gload16(const void* g, void* l) {
  __builtin_amdgcn_global_load_lds(
      (const __attribute__((address_space(1))) void*)g,
      (__attribute__((address_space(3))) void*)l, 16, 0, 0);
}
__device__ inline void gload4(const void* g, void* l) {
  __builtin_amdgcn_global_load_lds(
      (const __attribute__((address_space(1))) void*)g,
      (__attribute__((address_space(3))) void*)l, 4, 0, 0);
}

// Quantize 4 floats (optionally pre-scaled) to int8 hi/lo pairs packed into
// one int each (byte j = element j).
__device__ inline void q4(float4 v, float pre, int& hw, int& lw) {
  float xs[4] = {v.x, v.y, v.z, v.w};
  int h = 0, l = 0;
#pragma unroll
  for (int j = 0; j < 4; ++j) {
    float x = xs[j] * pre;
    float hf = rintf(fminf(fmaxf(x * S1, -127.f), 127.f));
    float rf = x - hf * S1_INV;
    float lf = rintf(fminf(fmaxf(rf * S2, -127.f), 127.f));
    h |= ((int)hf & 255) << (8 * j);
    l |= ((int)lf & 255) << (8 * j);
  }
  hw = h;
  lw = l;
}

// ---------------------------------------------------------------------------
// FUSED conversion + s: Xtr f32 -> int8 hi/lo fragment-tiled planes
// ([plane(2)][kf(4)][lk(2)][row(32)][16B] per 32-row 8 KB tile) AND
// s[m] = exp(-||y_m||^2/2) * w[m] via 8-lane in-wave reduction.
// One thread per 16B granule (8 threads per row, contiguous lanes).
// ---------------------------------------------------------------------------
__global__ __launch_bounds__(256) void gk_conv_s(const float* __restrict__ Xtr,
                                                 const float* __restrict__ wts,
                                                 char* __restrict__ planes,
                                                 float* __restrict__ s, int M) {
  int g = blockIdx.x * 256 + threadIdx.x;  // granule id: row*8 + gr
  int row = g >> 3;
  int gr = g & 7;  // 16 k-elems: kf = gr>>1, lk = gr&1
  if (row >= M) return;
  const float* p = Xtr + (size_t)row * 128 + gr * 16;
  int hw[4], lw[4];
  float ss = 0.f;
#pragma unroll
  for (int i = 0; i < 4; ++i) {
    float4 v = *(const float4*)(p + i * 4);
    ss += v.x * v.x + v.y * v.y + v.z * v.z + v.w * v.w;
    q4(v, 1.0f, hw[i], lw[i]);
  }
  // reduce over the 8 lanes of this row (lanes differ in bits 0..2)
  ss += __shfl_xor(ss, 1, 64);
  ss += __shfl_xor(ss, 2, 64);
  ss += __shfl_xor(ss, 4, 64);
  if (gr == 0) s[row] = expf(-0.5f * ss) * wts[row];

  int T = row >> 5, r = row & 31;
  size_t base = (size_t)T * 8192 + (gr >> 1) * 1024 + (gr & 1) * 512 + r * 16;
  *(i32x4*)(planes + base) = (i32x4){hw[0], hw[1], hw[2], hw[3]};
  *(i32x4*)(planes + base + 4096) = (i32x4){lw[0], lw[1], lw[2], lw[3]};
}

// ---------------------------------------------------------------------------
// Main kernel (i8x2, 2-deep accumulator pipeline, counted-vmcnt 4-buffer).
// Block = 512 thr = 8 waves; wave tile = 32 A-rows x 32 B-cols.
// Pipeline per iter t: [sched_barrier; issue stage(t+2) -> buf (t+2)&3;
// 12 MFMA(t) -> accCur; EPILOGUE(accPrev, tile t-1) in the SAME region
// (independent regs -> VALU overlaps MFMA issue; hides the acc/AGPR reads);
// s_waitcnt vmcnt(2) (own stage(t+1) landed; cross-wave via barrier);
// s_barrier]. WAR safe: stage(t+2) writes buf (t-2)&3 (readers done 2
// barriers ago); EPI(t-1) finishes before the barrier that precedes
// stage(t+3)'s issue. Tail uses a clamped dummy stage for uniform counts.
// pref[n] computed IN-REGISTER from the same Xnew loads used for B-quant.
// Grid 32x16 = 512 blocks = 2/CU; LDS 4x8192 + 4x256 = 33792 B.
// ---------------------------------------------------------------------------
__global__ __launch_bounds__(512, 4) void gk_main_i8(
    const float* __restrict__ Xnew, const char* __restrict__ planes,
    const float* __restrict__ s, float* __restrict__ out, int N, int M,
    int mchunk) {
  extern __shared__ char dlds[];  // [4 x 8192 A-bufs][4 x 256 s-bufs]

  const int t = threadIdx.x;
  const int l = t & 63;
  const int w = t >> 6;   // wave 0..7
  const int cl = l & 31;  // B-col within frag / A-row within frag
  const int lk = l >> 5;  // k-chunk half

  const int n0 = blockIdx.x * 256;
  const int M0 = blockIdx.y * mchunk;
  const int iters = mchunk >> 5;  // 64 (even, >= 4)
  const int T0 = M0 >> 5;

#define STAGE(tt)                                                       \
  {                                                                     \
    int st_ = ((tt) < iters) ? (tt) : (iters - 1); /* clamped dummy */  \
    gload16(planes + (size_t)(T0 + st_) * 8192 + t * 16,                \
            dlds + ((tt)&3) * 8192 + t * 16);                           \
    gload4(s + M0 + st_ * 32 + l, dlds + 32768 + ((tt)&3) * 256);       \
  }

#define COMPUTE(acc_hh, acc_m, tile)                                    \
  {                                                                     \
    const char* buf_ = dlds + ((tile)&3) * 8192;                        \
    acc_hh = zero16;                                                    \
    acc_m = zero16;                                                     \
    __builtin_amdgcn_s_setprio(1);                                      \
    _Pragma("unroll") for (int kf = 0; kf < 4; ++kf) {                  \
      const char* kb_ = buf_ + kf * 1024 + lk * 512 + cl * 16;          \
      i32x4 ah_ = *(const i32x4*)(kb_);                                 \
      i32x4 al_ = *(const i32x4*)(kb_ + 4096);                          \
      acc_hh = __builtin_amdgcn_mfma_i32_32x32x32_i8(ah_, bh[kf], acc_hh, 0, 0, 0); \
      acc_m = __builtin_amdgcn_mfma_i32_32x32x32_i8(ah_, bl[kf], acc_m, 0, 0, 0);   \
      acc_m = __builtin_amdgcn_mfma_i32_32x32x32_i8(al_, bh[kf], acc_m, 0, 0, 0);   \
    }                                                                   \
    __builtin_amdgcn_s_setprio(0);                                      \
  }

  // epilogue: c = ((hh<<8)+m)*2^-16 = log2e*<x,y>; exp2; * s[m].
  // C/D layout (verified): col = lane&31, row = (reg&3)+8*(reg>>2)+4*lk
#define EPI(acc_hh, acc_m, tile)                                        \
  {                                                                     \
    const float4* sl4_ =                                                \
        (const float4*)(dlds + 32768 + ((tile)&3) * 256);               \
    _Pragma("unroll") for (int q = 0; q < 4; ++q) {                     \
      float4 sv_ = sl4_[q * 2 + lk];                                    \
      _Pragma("unroll") for (int j = 0; j < 4; ++j) {                   \
        int r_ = q * 4 + j;                                             \
        float c_ = (float)((acc_hh[r_] << 8) + acc_m[r_]) * K2;         \
        out0 += fast_exp2(c_) * (&sv_.x)[j];                            \
      }                                                                 \
    }                                                                   \
  }

  const i32x16 zero16 = {0, 0, 0, 0, 0, 0, 0, 0, 0, 0, 0, 0, 0, 0, 0, 0};

  // ---- issue stage(0), stage(1) first so DMA overlaps B-init --------------
  STAGE(0);
  STAGE(1);

  // ---- per-wave B-panel (32 cols x K=128, i8 hi/lo, log2e folded) and
  // ---- in-register pref for the wave's cols (reuses the same loads) -------
  i32x4 bh[4], bl[4];
  float pref;
  {
    float ss = 0.f;
    const float* pc = Xnew + (size_t)(n0 + w * 32 + cl) * 128;
#pragma unroll
    for (int kf = 0; kf < 4; ++kf) {
      const float* p = pc + kf * 32 + lk * 16;
      int hw[4], lw[4];
#pragma unroll
      for (int i = 0; i < 4; ++i) {
        float4 v = *(const float4*)(p + i * 4);
        ss += v.x * v.x + v.y * v.y + v.z * v.z + v.w * v.w;
        q4(v, LOG2E, hw[i], lw[i]);
      }
      bh[kf] = (i32x4){hw[0], hw[1], hw[2], hw[3]};
      bl[kf] = (i32x4){lw[0], lw[1], lw[2], lw[3]};
    }
    ss += __shfl_xor(ss, 32, 64);  // combine the two k-halves of the col
    pref = expf(-0.5f * ss);
  }

  float out0 = 0.f;
  i32x16 hhA, mA, hhB, mB;

  asm volatile("s_waitcnt vmcnt(2)" ::: "memory");  // own stage(0) landed
  __builtin_amdgcn_s_barrier();                     // all waves' stage(0) in

  // ---- iter 0 (peeled: no previous acc to epilogue) -----------------------
  __builtin_amdgcn_sched_barrier(0);
  STAGE(2);
  COMPUTE(hhA, mA, 0);
  asm volatile("s_waitcnt vmcnt(2)" ::: "memory");
  __builtin_amdgcn_s_barrier();

  // ---- pairs t = (tt, tt+1), tt = 1,3,...,iters-3 -------------------------
#pragma unroll 1
  for (int tt = 1; tt < iters - 1; tt += 2) {
    __builtin_amdgcn_sched_barrier(0);
    STAGE(tt + 2);
    COMPUTE(hhB, mB, tt);
    EPI(hhA, mA, tt - 1);
    asm volatile("s_waitcnt vmcnt(2)" ::: "memory");
    __builtin_amdgcn_s_barrier();

    __builtin_amdgcn_sched_barrier(0);
    STAGE(tt + 3);
    COMPUTE(hhA, mA, tt + 1);
    EPI(hhB, mB, tt);
    asm volatile("s_waitcnt vmcnt(2)" ::: "memory");
    __builtin_amdgcn_s_barrier();
  }

  // ---- tail: tile iters-1, then drain both epilogues ----------------------
  __builtin_amdgcn_sched_barrier(0);
  COMPUTE(hhB, mB, iters - 1);
  EPI(hhA, mA, iters - 2);
  EPI(hhB, mB, iters - 1);

  // ---- reduce row-halves (lane>>5) + atomic -------------------------------
  out0 += __shfl_xor(out0, 32, 64);
  if (l < 32) {
    int n = n0 + w * 32 + l;
    atomicAdd(out + n, pref * out0);
  }
#undef STAGE
#undef COMPUTE
#undef EPI
}

// ---------------------------------------------------------------------------
// FALLBACK (ws too small): bf16x3 R1-structure (known-good ~185 us) + prep.
// ---------------------------------------------------------------------------
__global__ __launch_bounds__(256) void gk_prep(
    const float* __restrict__ Xnew, const float* __restrict__ Xtr,
    const float* __restrict__ w, float* __restrict__ s,
    float* __restrict__ pref, int M, int N) {
  int row = blockIdx.x * 4 + (threadIdx.x >> 6);
  int lane = threadIdx.x & 63;
  if (row >= M + N) return;
  const float* src =
      (row < M) ? (Xtr + (size_t)row * 128) : (Xnew + (size_t)(row - M) * 128);
  float2 v = *(const float2*)(src + lane * 2);
  float ss = v.x * v.x + v.y * v.y;
#pragma unroll
  for (int o = 32; o >= 1; o >>= 1) ss += __shfl_xor(ss, o, 64);
  if (lane == 0) {
    float e = expf(-0.5f * ss);
    if (row < M)
      s[row] = e * w[row];
    else
      pref[row - M] = e;
  }
}

__device__ inline unsigned swz_fb(unsigned off) {
  return off ^ (((off >> 8) & 7u) << 4);
}
__device__ inline void split8(float x0, float x1, float x2, float x3,
                              float x4, float x5, float x6, float x7,
                              float scale, short8& hi, short8& lo) {
  float xs[8] = {x0, x1, x2, x3, x4, x5, x6, x7};
#pragma unroll
  for (int i = 0; i < 8; ++i) {
    float v = xs[i] * scale;
    unsigned u = __float_as_uint(v);
    float hf = __uint_as_float(u & 0xffff0000u);
    float rr = v - hf;
    hi[i] = (short)(u >> 16);
    lo[i] = (short)(__float_as_uint(rr) >> 16);
  }
}

__global__ __launch_bounds__(256, 2) void gk_main_fb(
    const float* __restrict__ Xnew, const float* __restrict__ Xtr,
    const float* __restrict__ s, const float* __restrict__ pref,
    float* __restrict__ out, int N, int M, int mchunk) {
  __shared__ __attribute__((aligned(16))) char lds[33024];
  const int t = threadIdx.x;
  const int l = t & 63;
  const int w = t >> 6;
  const int lrow = l & 31;
  const int lk = l >> 5;
  const int n0 = blockIdx.x * 256;
  const int M0 = blockIdx.y * mchunk;
  const int iters = mchunk >> 6;

  short8 bh[2][8], bl[2][8];
  {
    const int colbase = n0 + w * 64;
#pragma unroll
    for (int nf = 0; nf < 2; ++nf) {
      int col = colbase + nf * 32 + lrow;
      const float* p = Xnew + (size_t)col * 128 + lk * 8;
#pragma unroll
      for (int kf = 0; kf < 8; ++kf) {
        float4 f0 = *(const float4*)(p + kf * 16);
        float4 f1 = *(const float4*)(p + kf * 16 + 4);
        split8(f0.x, f0.y, f0.z, f0.w, f1.x, f1.y, f1.z, f1.w, LOG2E,
               bh[nf][kf], bl[nf][kf]);
      }
    }
  }

  float out0 = 0.f, out1 = 0.f;
  float4 ga[4][2];
  float sreg = 0.f;
  {
    const float* abase = Xtr + (size_t)M0 * 128;
#pragma unroll
    for (int j = 0; j < 4; ++j) {
      int c = t + j * 256;
      int row = c >> 4, oct = c & 15;
      const float* p = abase + (size_t)row * 128 + oct * 8;
      ga[j][0] = *(const float4*)p;
      ga[j][1] = *(const float4*)(p + 4);
    }
    if (t < 64) sreg = s[M0 + t];
  }

#pragma unroll 1
  for (int it = 0; it < iters; ++it) {
    __syncthreads();
#pragma unroll
    for (int j = 0; j < 4; ++j) {
      int c = t + j * 256;
      int row = c >> 4, oct = c & 15;
      unsigned off = swz_fb((unsigned)(row * 256 + oct * 16));
      short8 hi, lo;
      split8(ga[j][0].x, ga[j][0].y, ga[j][0].z, ga[j][0].w, ga[j][1].x,
             ga[j][1].y, ga[j][1].z, ga[j][1].w, 1.0f, hi, lo);
      *(short8*)(lds + off) = hi;
      *(short8*)(lds + 16384 + off) = lo;
    }
    if (t < 64) *(float*)(lds + 32768 + t * 4) = sreg;
    __syncthreads();
    if (it + 1 < iters) {
      const float* abase = Xtr + (size_t)(M0 + (it + 1) * 64) * 128;
#pragma unroll
      for (int j = 0; j < 4; ++j) {
        int c = t + j * 256;
        int row = c >> 4, oct = c & 15;
        const float* p = abase + (size_t)row * 128 + oct * 8;
        ga[j][0] = *(const float4*)p;
        ga[j][1] = *(const float4*)(p + 4);
      }
      if (t < 64) sreg = s[M0 + (it + 1) * 64 + t];
    }
#pragma unroll
    for (int mf = 0; mf < 2; ++mf) {
      f32x16 acc0 = {0, 0, 0, 0, 0, 0, 0, 0, 0, 0, 0, 0, 0, 0, 0, 0};
      f32x16 acc1 = {0, 0, 0, 0, 0, 0, 0, 0, 0, 0, 0, 0, 0, 0, 0, 0};
#pragma unroll
      for (int kf = 0; kf < 8; ++kf) {
        unsigned off =
            swz_fb((unsigned)((mf * 32 + lrow) * 256 + kf * 32 + lk * 16));
        short8 ah = *(const short8*)(lds + off);
        short8 al = *(const short8*)(lds + 16384 + off);
        acc0 = __builtin_amdgcn_mfma_f32_32x32x16_bf16(ah, bh[0][kf], acc0, 0, 0, 0);
        acc1 = __builtin_amdgcn_mfma_f32_32x32x16_bf16(ah, bh[1][kf], acc1, 0, 0, 0);
        acc0 = __builtin_amdgcn_mfma_f32_32x32x16_bf16(ah, bl[0][kf], acc0, 0, 0, 0);
        acc1 = __builtin_amdgcn_mfma_f32_32x32x16_bf16(ah, bl[1][kf], acc1, 0, 0, 0);
        acc0 = __builtin_amdgcn_mfma_f32_32x32x16_bf16(al, bh[0][kf], acc0, 0, 0, 0);
        acc1 = __builtin_amdgcn_mfma_f32_32x32x16_bf16(al, bh[1][kf], acc1, 0, 0, 0);
      }
      const float* sl = (const float*)(lds + 32768 + mf * 128);
#pragma unroll
      for (int r = 0; r < 16; ++r) {
        int row = (r & 3) + 8 * (r >> 2) + 4 * lk;
        float sv = sl[row];
        out0 += fast_exp2(acc0[r]) * sv;
        out1 += fast_exp2(acc1[r]) * sv;
      }
    }
  }
  out0 += __shfl_xor(out0, 32, 64);
  out1 += __shfl_xor(out1, 32, 64);
  if (l < 32) {
    int n = n0 + w * 64 + l;
    atomicAdd(out + n, pref[n] * out0);
    n += 32;
    atomicAdd(out + n, pref[n] * out1);
  }
}

extern "C" void kernel_launch(void* const* d_in, const int* in_sizes, int n_in,
                              void* d_out, int out_size, void* d_ws,
                              size_t ws_size, hipStream_t stream) {
  const float* Xnew = (const float*)d_in[0];
  const float* Xtr = (const float*)d_in[1];
  const float* wts = (const float*)d_in[2];
  float* out = (float*)d_out;

  const int N = in_sizes[0] / 128;  // 8192
  const int M = in_sizes[1] / 128;  // 32768

  char* ws = (char*)d_ws;
  float* s_ws = (float*)ws;                 // [M]
  char* planes_ws = ws + (size_t)M * 4;     // [M*256 B], 16B-aligned
  const size_t need = (size_t)M * 4 + (size_t)M * 256;

  hipMemsetAsync(d_out, 0, (size_t)N * sizeof(float), stream);

  if (ws_size >= need) {
    gk_conv_s<<<dim3(M * 8 / 256), 256, 0, stream>>>(Xtr, wts, planes_ws,
                                                     s_ws, M);
    const int SPLIT = 16;  // 32 x 16 = 512 blocks = exactly 2 per CU
    dim3 grid(N / 256, SPLIT);
    gk_main_i8<<<grid, 512, 33792, stream>>>(Xnew, planes_ws, s_ws, out, N, M,
                                             M / SPLIT);
  } else {
    // fallback needs s + pref arrays
    float* pref_ws = s_ws + M;
    int rows = M + N;
    gk_prep<<<dim3((rows + 3) / 4), 256, 0, stream>>>(Xnew, Xtr, wts, s_ws,
                                                      pref_ws, M, N);
    const int SPLIT = 16;
    dim3 grid(N / 256, SPLIT);
    gk_main_fb<<<grid, 256, 0, stream>>>(Xnew, Xtr, s_ws, pref_ws, out, N, M,
                                         M / SPLIT);
  }
}